// Round 6
// baseline (425.206 us; speedup 1.0000x reference)
//
#include <hip/hip_runtime.h>
#include <hip/hip_bf16.h>

#define GN 8192
#define KD 256
#define OD 64
#define LOG2E 1.44269504f

typedef __attribute__((ext_vector_type(8))) short bf16x8;
typedef __attribute__((ext_vector_type(4))) float f32x4;

__device__ __forceinline__ float fexp2(float x) {
#if __has_builtin(__builtin_amdgcn_exp2f)
  return __builtin_amdgcn_exp2f(x);
#else
  return exp2f(x);
#endif
}

#if __has_builtin(__builtin_amdgcn_sched_barrier)
#define SCHED_FENCE() __builtin_amdgcn_sched_barrier(0)
#else
#define SCHED_FENCE()
#endif

// ---------------------------------------------------------------------------
// Kernel 1: h = input @ W (fp32). Emits hT (bf16 [OD][GN]), f1p/f2p fp32
// pre-scaled by log2(e), and the 3 scalar e-outputs.
// ---------------------------------------------------------------------------
__global__ __launch_bounds__(256) void gat_k1(
    const float* __restrict__ input, const float* __restrict__ W,
    const float* __restrict__ a, __hip_bfloat16* __restrict__ hT,
    float* __restrict__ f1p, float* __restrict__ f2p, float* __restrict__ out)
{
  __shared__ float Wl[KD * OD];        // 64 KB, [k][c]
  __shared__ float inT[KD * 33];       // [k][r], pad 33
  __shared__ float red1[8][32];
  __shared__ float red2[8][32];
  __shared__ float s1row[32];
  __shared__ float s2row[32];

  const int tid = threadIdx.x;
  const int i0 = blockIdx.x * 32;

  for (int idx = tid; idx < KD * OD / 4; idx += 256)
    ((float4*)Wl)[idx] = ((const float4*)W)[idx];

#pragma unroll
  for (int it = 0; it < 8; ++it) {
    int idx = tid + it * 256;
    int r = idx >> 6, k4 = idx & 63;
    float4 v = *(const float4*)(input + (long)(i0 + r) * KD + k4 * 4);
    inT[(k4 * 4 + 0) * 33 + r] = v.x;
    inT[(k4 * 4 + 1) * 33 + r] = v.y;
    inT[(k4 * 4 + 2) * 33 + r] = v.z;
    inT[(k4 * 4 + 3) * 33 + r] = v.w;
  }
  __syncthreads();

  const int r = tid & 31;
  const int cg = tid >> 5;
  float acc[8];
#pragma unroll
  for (int c = 0; c < 8; ++c) acc[c] = 0.f;

#pragma unroll 4
  for (int k = 0; k < KD; ++k) {
    float inv = inT[k * 33 + r];
    float4 wa = *(const float4*)&Wl[k * 64 + cg * 8];
    float4 wb = *(const float4*)&Wl[k * 64 + cg * 8 + 4];
    acc[0] += inv * wa.x; acc[1] += inv * wa.y;
    acc[2] += inv * wa.z; acc[3] += inv * wa.w;
    acc[4] += inv * wb.x; acc[5] += inv * wb.y;
    acc[6] += inv * wb.z; acc[7] += inv * wb.w;
  }

#pragma unroll
  for (int c = 0; c < 8; ++c)
    hT[(long)(cg * 8 + c) * GN + i0 + r] = __float2bfloat16(acc[c]);

  float s1 = 0.f, s2 = 0.f;
#pragma unroll
  for (int c = 0; c < 8; ++c) {
    s1 += acc[c] * a[cg * 8 + c];
    s2 += acc[c] * a[OD + cg * 8 + c];
  }
  red1[cg][r] = s1; red2[cg][r] = s2;
  __syncthreads();
  if (tid < 32) {
    float f1 = 0.f, f2 = 0.f;
#pragma unroll
    for (int g = 0; g < 8; ++g) { f1 += red1[g][tid]; f2 += red2[g][tid]; }
    s1row[tid] = f1; s2row[tid] = f2;
    f1p[i0 + tid] = f1 * LOG2E;
    f2p[i0 + tid] = f2 * LOG2E;
  }
  __syncthreads();
  if (blockIdx.x == 0 && tid == 0) {
    float e12 = s1row[1] + s2row[2];
    float e13 = s1row[1] + s2row[3];
    float e32 = s1row[3] + s2row[2];
    out[(long)GN * OD + 0] = fmaxf(e12, 0.01f * e12);
    out[(long)GN * OD + 1] = fmaxf(e13, 0.01f * e13);
    out[(long)GN * OD + 2] = fmaxf(e32, 0.01f * e32);
  }
}

// ---------------------------------------------------------------------------
// Kernel 2: fused mask+softmax(no-max)+alpha@h.
// Barrier-free main loop; adj loaded DIRECTLY in A-frag layout from global
// with a 4-slice-deep rotating register prefetch (adj + B-frags), keeping
// ~24 KB per wave continuously in flight (Little's law >> 6.3 TB/s need).
// f2 lives in LDS (loaded once, broadcast reads, no vmem FIFO pollution).
// 512 blocks x 256 threads = 2 blocks/CU; wave = 16 rows x 2048-j quarter.
// ---------------------------------------------------------------------------
struct Asl { int4 a0, a1; };
struct Bsl { bf16x8 b0, b1, b2, b3; };

__global__ __launch_bounds__(256, 2) void gat_k2(
    const int* __restrict__ adj, const __hip_bfloat16* __restrict__ hT,
    const float* __restrict__ f1p, const float* __restrict__ f2p,
    float* __restrict__ out)
{
  __shared__ float f2l[GN];            // 32 KB; epilogue overlays pb/sb

  const int tid = threadIdx.x;
  const int lane = tid & 63;
  const int wv = tid >> 6;             // j-quarter 0..3
  const int tn = lane & 15;            // MFMA m/n index (row)
  const int quad = lane >> 4;          // MFMA k-quad
  const int i0 = blockIdx.x * 16;
  const int jq = wv * 2048;

  // stage f2 (whole 8192-row, 32 KB) into LDS once
  for (int i = tid; i < GN / 4; i += 256)
    ((float4*)f2l)[i] = ((const float4*)f2p)[i];

  const float f1r = f1p[i0 + tn];
  __syncthreads();

  const int* ap = adj + (long)(i0 + tn) * GN + jq + quad * 8;
  const __hip_bfloat16* hp = hT + (long)tn * GN + jq + quad * 8;
  const float* f2q = f2l + jq + quad * 8;

  f32x4 acc[4];
#pragma unroll
  for (int nf = 0; nf < 4; ++nf) acc[nf] = (f32x4){0.f, 0.f, 0.f, 0.f};
  f32x4 accS = (f32x4){0.f, 0.f, 0.f, 0.f};

  bf16x8 ones;  // ones in column n==0 -> row sums via MFMA
  {
    short ov = (tn == 0) ? (short)0x3F80 : (short)0;
#pragma unroll
    for (int i = 0; i < 8; ++i) ones[i] = ov;
  }

  auto loadA = [&](int s) {
    Asl r;
    r.a0 = *(const int4*)(ap + s * 32);
    r.a1 = *(const int4*)(ap + s * 32 + 4);
    return r;
  };
  auto loadB = [&](int s) {
    Bsl r;
    r.b0 = *(const bf16x8*)(hp + 0 * 16 * (long)GN + s * 32);
    r.b1 = *(const bf16x8*)(hp + 1 * 16 * (long)GN + s * 32);
    r.b2 = *(const bf16x8*)(hp + 2 * 16 * (long)GN + s * 32);
    r.b3 = *(const bf16x8*)(hp + 3 * 16 * (long)GN + s * 32);
    return r;
  };
  auto computeSlice = [&](int s, const Asl& ca, const Bsl& cb) {
    const float4 f20 = *(const float4*)(f2q + s * 32);
    const float4 f21 = *(const float4*)(f2q + s * 32 + 4);
    float e0 = f1r + f20.x, e1 = f1r + f20.y, e2 = f1r + f20.z, e3 = f1r + f20.w;
    float e4 = f1r + f21.x, e5 = f1r + f21.y, e6 = f1r + f21.z, e7 = f1r + f21.w;
    float v0 = fexp2((ca.a0.x > 0) ? fmaxf(e0, 0.01f * e0) : -256.f);
    float v1 = fexp2((ca.a0.y > 0) ? fmaxf(e1, 0.01f * e1) : -256.f);
    float v2 = fexp2((ca.a0.z > 0) ? fmaxf(e2, 0.01f * e2) : -256.f);
    float v3 = fexp2((ca.a0.w > 0) ? fmaxf(e3, 0.01f * e3) : -256.f);
    float v4 = fexp2((ca.a1.x > 0) ? fmaxf(e4, 0.01f * e4) : -256.f);
    float v5 = fexp2((ca.a1.y > 0) ? fmaxf(e5, 0.01f * e5) : -256.f);
    float v6 = fexp2((ca.a1.z > 0) ? fmaxf(e6, 0.01f * e6) : -256.f);
    float v7 = fexp2((ca.a1.w > 0) ? fmaxf(e7, 0.01f * e7) : -256.f);
    union { bf16x8 v; unsigned u[4]; } wf;
    wf.u[0] = __builtin_amdgcn_perm(__float_as_uint(v1), __float_as_uint(v0), 0x07060302u);
    wf.u[1] = __builtin_amdgcn_perm(__float_as_uint(v3), __float_as_uint(v2), 0x07060302u);
    wf.u[2] = __builtin_amdgcn_perm(__float_as_uint(v5), __float_as_uint(v4), 0x07060302u);
    wf.u[3] = __builtin_amdgcn_perm(__float_as_uint(v7), __float_as_uint(v6), 0x07060302u);
    acc[0] = __builtin_amdgcn_mfma_f32_16x16x32_bf16(wf.v, cb.b0, acc[0], 0, 0, 0);
    acc[1] = __builtin_amdgcn_mfma_f32_16x16x32_bf16(wf.v, cb.b1, acc[1], 0, 0, 0);
    acc[2] = __builtin_amdgcn_mfma_f32_16x16x32_bf16(wf.v, cb.b2, acc[2], 0, 0, 0);
    acc[3] = __builtin_amdgcn_mfma_f32_16x16x32_bf16(wf.v, cb.b3, acc[3], 0, 0, 0);
    accS   = __builtin_amdgcn_mfma_f32_16x16x32_bf16(wf.v, ones,  accS,   0, 0, 0);
  };

  // prologue: 4-deep pipeline warmup
  Asl A0 = loadA(0), A1 = loadA(1), A2 = loadA(2), A3 = loadA(3);
  Bsl B0 = loadB(0), B1 = loadB(1), B2 = loadB(2), B3 = loadB(3);
  SCHED_FENCE();

  for (int t = 0; t < 16; ++t) {
    const int s = t * 4;
    {
      Asl ca = A0; Bsl cb = B0;
      if (s + 4 < 64) { A0 = loadA(s + 4); B0 = loadB(s + 4); }
      SCHED_FENCE();
      computeSlice(s, ca, cb);
    }
    {
      Asl ca = A1; Bsl cb = B1;
      if (s + 5 < 64) { A1 = loadA(s + 5); B1 = loadB(s + 5); }
      SCHED_FENCE();
      computeSlice(s + 1, ca, cb);
    }
    {
      Asl ca = A2; Bsl cb = B2;
      if (s + 6 < 64) { A2 = loadA(s + 6); B2 = loadB(s + 6); }
      SCHED_FENCE();
      computeSlice(s + 2, ca, cb);
    }
    {
      Asl ca = A3; Bsl cb = B3;
      if (s + 7 < 64) { A3 = loadA(s + 7); B3 = loadB(s + 7); }
      SCHED_FENCE();
      computeSlice(s + 3, ca, cb);
    }
  }

  // epilogue: overlay pb/sb on f2l (all f2 reads done), reduce 4 j-quarters
  __syncthreads();
  float* pb = f2l;                 // [4][16][68]
  float* sb = f2l + 4 * 16 * 68;   // [4][16]
#pragma unroll
  for (int nf = 0; nf < 4; ++nf)
#pragma unroll
    for (int rgi = 0; rgi < 4; ++rgi)
      pb[(wv * 16 + quad * 4 + rgi) * 68 + nf * 16 + tn] = acc[nf][rgi];
  if (tn == 0) {
#pragma unroll
    for (int rgi = 0; rgi < 4; ++rgi)
      sb[wv * 16 + quad * 4 + rgi] = accS[rgi];
  }
  __syncthreads();
  for (int t = tid; t < 16 * OD; t += 256) {
    int rr = t >> 6, cc = t & 63;
    float num = pb[(0 * 16 + rr) * 68 + cc] + pb[(1 * 16 + rr) * 68 + cc] +
                pb[(2 * 16 + rr) * 68 + cc] + pb[(3 * 16 + rr) * 68 + cc];
    float den = sb[0 * 16 + rr] + sb[1 * 16 + rr] + sb[2 * 16 + rr] + sb[3 * 16 + rr];
    out[(long)(i0 + rr) * OD + cc] = num / den;
  }
}

extern "C" void kernel_launch(void* const* d_in, const int* in_sizes, int n_in,
                              void* d_out, int out_size, void* d_ws, size_t ws_size,
                              hipStream_t stream) {
  const float* input = (const float*)d_in[0];
  const int* adj     = (const int*)d_in[1];
  const float* W     = (const float*)d_in[2];
  const float* a     = (const float*)d_in[3];
  float* out = (float*)d_out;

  char* ws = (char*)d_ws;
  __hip_bfloat16* hT = (__hip_bfloat16*)ws;               // 1 MB
  float* f1p = (float*)(ws + (size_t)OD * GN * 2);        // 32 KB
  float* f2p = f1p + GN;                                  // 32 KB

  gat_k1<<<256, 256, 0, stream>>>(input, W, a, hT, f1p, f2p, out);
  gat_k2<<<512, 256, 0, stream>>>(adj, hT, f1p, f2p, out);
}